// Round 2
// baseline (4603.485 us; speedup 1.0000x reference)
//
#include <hip/hip_runtime.h>

// Problem constants: N=16, C_IN=32, C_OUT=64, H=W=128, D=5, K=800
#define R_SZ  (16*32*32*81)      // 1,327,104 floats
#define Q_SZ  (16*800*800)       // 10,240,000
#define P_SZ  (16*800*64)        // 819,200
#define LI_SZ (16*10*80*80)      // 1,024,000

typedef unsigned short u16;
typedef __attribute__((ext_vector_type(8))) short bf16x8;
typedef __attribute__((ext_vector_type(4))) float f32x4;

#define MFMA16(a, b, c) __builtin_amdgcn_mfma_f32_16x16x32_bf16(a, b, c, 0, 0, 0)

__device__ __forceinline__ float alpha_scale(const float* alpha, const float* reg, int n) {
  return alpha[n] * (16384.0f * reg[0] / 800.0f);
}

__device__ __forceinline__ u16 f2bf(float f) {
  union { float f; unsigned u; } v; v.f = f;
  unsigned r = v.u + 0x7FFFu + ((v.u >> 16) & 1u);
  return (u16)(r >> 16);
}
__device__ __forceinline__ float bf2f(u16 h) {
  union { unsigned u; float f; } v; v.u = ((unsigned)h) << 16; return v.f;
}

// Load 8 consecutive bf16 (8B-aligned) from LDS as an MFMA fragment.
__device__ __forceinline__ bf16x8 load8(const u16* p) {
  union { uint2 d[2]; bf16x8 v; } u;
  u.d[0] = *(const uint2*)p;
  u.d[1] = *(const uint2*)(p + 4);
  return u.v;
}

// Build a shifted fragment from a 16-element window held in 8 dwords.
// s = shift in elements (0..8). Odd s -> v_alignbit.
__device__ __forceinline__ bf16x8 build_frag(const unsigned* w, int s) {
  union { unsigned u[4]; bf16x8 v; } f;
  int b = s >> 1;
  if (s & 1) {
    #pragma unroll
    for (int k = 0; k < 4; ++k) f.u[k] = (w[b + k] >> 16) | (w[b + k + 1] << 16);
  } else {
    #pragma unroll
    for (int k = 0; k < 4; ++k) f.u[k] = w[b + k];
  }
  return f.v;
}

// Stage one image row (C channels, 128 px) into an LDS slot, split into
// bf16 hi (offset 0) and lo (offset partStride) parts. Row layout per part:
// [c][136 els], data at els [4,132), halo els stay zero (zeroed once at start).
__device__ __forceinline__ void stage_row(u16* slot, int partStride,
                                          const float* __restrict__ img,
                                          int C, int r, bool valid,
                                          int tid, int nthr) {
  for (int idx = tid; idx < C * 16; idx += nthr) {
    int c = idx >> 4, m = idx & 15;
    float v[8];
    if (valid) {
      const float* p = img + ((size_t)c * 128 + r) * 128 + m * 8;
      float4 a = *(const float4*)p;
      float4 b = *(const float4*)(p + 4);
      v[0]=a.x; v[1]=a.y; v[2]=a.z; v[3]=a.w; v[4]=b.x; v[5]=b.y; v[6]=b.z; v[7]=b.w;
    } else {
      #pragma unroll
      for (int k = 0; k < 8; ++k) v[k] = 0.0f;
    }
    union { u16 s[8]; uint2 d[2]; } hh, ll;
    #pragma unroll
    for (int k = 0; k < 8; ++k) {
      u16 h = f2bf(v[k]);
      hh.s[k] = h;
      ll.s[k] = f2bf(v[k] - bf2f(h));
    }
    u16* dh = slot + c * 136 + 4 + m * 8;
    *(uint2*)(dh)     = hh.d[0];
    *(uint2*)(dh + 4) = hh.d[1];
    u16* dl = dh + partStride;
    *(uint2*)(dl)     = ll.d[0];
    *(uint2*)(dl + 4) = ll.d[1];
  }
}

// -------------------- init: R = 0, P = a * d^T --------------------
__global__ void k_init(float* __restrict__ R, float* __restrict__ P,
                       const float* __restrict__ d, const float* __restrict__ alpha,
                       const float* __restrict__ reg) {
  int idx = blockIdx.x * 256 + threadIdx.x;
  if (idx < R_SZ) R[idx] = 0.0f;
  int e = idx - R_SZ;
  if (e >= 0 && e < P_SZ) {
    int n = e / 51200; int q = e % 51200;
    int co = q / 800;  int k = q % 800;
    float a = alpha_scale(alpha, reg, n);
    P[(n*800 + k)*64 + co] = a * d[(n*64 + co)*800 + k];
  }
}

// ---------------- R[n,c1,c2,u,v] = sum_ij x[c1,i,j]*x[c2,i+u-4,j+v-4] -------
// MFMA (bf16 hi/lo split, 3 passes). grid = 16(n) * 16(row chunks of 8).
// Block = 9 waves, wave w handles du = w-4. Sliding 9-row LDS window.
#define SLOT_US 8704     // ushorts per slot: 2 parts * 32 ch * 136
#define PSTR_32 4352     // part stride for 32-channel rows

__global__ __launch_bounds__(576) void k_corrR_mfma(const float* __restrict__ x,
                                                    float* __restrict__ R) {
  __shared__ u16 lds[9 * SLOT_US];   // 156,672 B
  int n  = blockIdx.x >> 4;
  int r0 = (blockIdx.x & 15) << 3;
  int tid = threadIdx.x;
  const float* xn = x + (size_t)n * 32 * 128 * 128;

  // zero halo els [0,4) and [132,136) for every (slot,part,channel): 576 items
  {
    int s = tid / 64, p = (tid >> 5) & 1, c = tid & 31;
    u16* b = lds + s * SLOT_US + p * PSTR_32 + c * 136;
    uint2 z; z.x = 0; z.y = 0;
    *(uint2*)b = z;
    *(uint2*)(b + 132) = z;
  }

  // initial window: rows r0-4 .. r0+4
  for (int rr = -4; rr <= 4; ++rr) {
    int r = r0 + rr;
    stage_row(lds + ((r + 18) % 9) * SLOT_US, PSTR_32, xn, 32, r,
              (r >= 0 && r < 128), tid, 576);
  }

  int wave = tid >> 6;          // 0..8
  int lane = tid & 63;
  int du = wave - 4;
  int lm = lane & 15, q = lane >> 4;

  f32x4 acc[9][2][2];
  #pragma unroll
  for (int dv = 0; dv < 9; ++dv)
    #pragma unroll
    for (int mt = 0; mt < 2; ++mt)
      #pragma unroll
      for (int nt = 0; nt < 2; ++nt)
        acc[dv][mt][nt] = (f32x4){0.f, 0.f, 0.f, 0.f};

  for (int i = r0; i < r0 + 8; ++i) {
    __syncthreads();
    const u16* A  = lds + ((i + 18) % 9) * SLOT_US;
    const u16* Bp = lds + ((i + du + 18) % 9) * SLOT_US;
    #pragma unroll
    for (int ks = 0; ks < 4; ++ks) {
      int kb = ks * 32 + q * 8;
      bf16x8 af[2][2];
      #pragma unroll
      for (int pa = 0; pa < 2; ++pa)
        #pragma unroll
        for (int mt = 0; mt < 2; ++mt)
          af[pa][mt] = load8(A + pa * PSTR_32 + (mt * 16 + lm) * 136 + 4 + kb);
      #pragma unroll
      for (int nt = 0; nt < 2; ++nt)
        #pragma unroll
        for (int pb = 0; pb < 2; ++pb) {
          const u16* wp = Bp + pb * PSTR_32 + (nt * 16 + lm) * 136 + kb; // el j-4
          unsigned w[8];
          #pragma unroll
          for (int k = 0; k < 4; ++k) {
            uint2 t = *(const uint2*)(wp + k * 4);
            w[2 * k] = t.x; w[2 * k + 1] = t.y;
          }
          #pragma unroll
          for (int dv = 0; dv < 9; ++dv) {
            bf16x8 bf = build_frag(w, dv);
            #pragma unroll
            for (int mt = 0; mt < 2; ++mt)
              #pragma unroll
              for (int pa = 0; pa < 2; ++pa) {
                if (pa == 1 && pb == 1) continue;   // skip lo*lo pass
                acc[dv][mt][nt] = MFMA16(af[pa][mt], bf, acc[dv][mt][nt]);
              }
          }
        }
    }
    __syncthreads();
    if (i + 1 < r0 + 8) {
      int r = i + 5;
      stage_row(lds + ((r + 18) % 9) * SLOT_US, PSTR_32, xn, 32, r,
                (r >= 0 && r < 128), tid, 576);
    }
  }

  // write out: C/D layout col=lane&15 (c2-in-tile), row=q*4+reg (c1-in-tile)
  float* Rn = R + (size_t)n * 32 * 32 * 81;
  int u = du + 4;
  #pragma unroll
  for (int dv = 0; dv < 9; ++dv)
    #pragma unroll
    for (int mt = 0; mt < 2; ++mt)
      #pragma unroll
      for (int nt = 0; nt < 2; ++nt)
        #pragma unroll
        for (int r = 0; r < 4; ++r) {
          int c1 = mt * 16 + q * 4 + r;
          int c2 = nt * 16 + lm;
          atomicAdd(&Rn[(c1 * 32 + c2) * 81 + u * 9 + dv], acc[dv][mt][nt][r]);
        }
}

// ------- P[n,(ci,a,e),co] += sum_ij y[co,i,j]*x[ci,i+a-2,j+e-2]  (MFMA) -----
// grid = 16(n) * 16(row chunks of 8). Block = 10 waves: wave = (du+2)*2 + mhalf.
#define YPSTR 8704   // part stride for 64-channel y rows (64*136)

__global__ __launch_bounds__(640) void k_corrP_mfma(const float* __restrict__ x,
                                                    const float* __restrict__ y,
                                                    float* __restrict__ P) {
  __shared__ u16 xs[5 * SLOT_US];   // 87,040 B
  __shared__ u16 ys[2 * YPSTR];     // 34,816 B
  int n  = blockIdx.x >> 4;
  int r0 = (blockIdx.x & 15) << 3;
  int tid = threadIdx.x;
  const float* xn = x + (size_t)n * 32 * 128 * 128;
  const float* yn = y + (size_t)n * 64 * 128 * 128;

  // zero x halos: 5 slots * 2 parts * 32 ch = 320 items
  if (tid < 320) {
    int s = tid / 64, p = (tid >> 5) & 1, c = tid & 31;
    u16* b = xs + s * SLOT_US + p * PSTR_32 + c * 136;
    uint2 z; z.x = 0; z.y = 0;
    *(uint2*)b = z;
    *(uint2*)(b + 132) = z;
  }

  for (int rr = -2; rr <= 2; ++rr) {
    int r = r0 + rr;
    stage_row(xs + ((r + 10) % 5) * SLOT_US, PSTR_32, xn, 32, r,
              (r >= 0 && r < 128), tid, 640);
  }
  stage_row(ys, YPSTR, yn, 64, r0, true, tid, 640);

  int wave = tid >> 6;            // 0..9
  int lane = tid & 63;
  int du = (wave >> 1) - 2;
  int mh = wave & 1;              // which half of the 64 y-channels
  int lm = lane & 15, q = lane >> 4;

  f32x4 acc[5][2][2];
  #pragma unroll
  for (int dv = 0; dv < 5; ++dv)
    #pragma unroll
    for (int mt = 0; mt < 2; ++mt)
      #pragma unroll
      for (int nt = 0; nt < 2; ++nt)
        acc[dv][mt][nt] = (f32x4){0.f, 0.f, 0.f, 0.f};

  for (int i = r0; i < r0 + 8; ++i) {
    __syncthreads();
    const u16* A  = ys;
    const u16* Bp = xs + ((i + du + 10) % 5) * SLOT_US;
    #pragma unroll
    for (int ks = 0; ks < 4; ++ks) {
      int kb = ks * 32 + q * 8;
      bf16x8 af[2][2];
      #pragma unroll
      for (int pa = 0; pa < 2; ++pa)
        #pragma unroll
        for (int mt = 0; mt < 2; ++mt)
          af[pa][mt] = load8(A + pa * YPSTR + (mh * 32 + mt * 16 + lm) * 136 + 4 + kb);
      #pragma unroll
      for (int nt = 0; nt < 2; ++nt)
        #pragma unroll
        for (int pb = 0; pb < 2; ++pb) {
          const u16* wp = Bp + pb * PSTR_32 + (nt * 16 + lm) * 136 + kb;
          unsigned w[8];
          #pragma unroll
          for (int k = 0; k < 4; ++k) {
            uint2 t = *(const uint2*)(wp + k * 4);
            w[2 * k] = t.x; w[2 * k + 1] = t.y;
          }
          #pragma unroll
          for (int dv = 0; dv < 5; ++dv) {
            bf16x8 bf = build_frag(w, dv + 2);
            #pragma unroll
            for (int mt = 0; mt < 2; ++mt)
              #pragma unroll
              for (int pa = 0; pa < 2; ++pa) {
                if (pa == 1 && pb == 1) continue;   // skip lo*lo
                acc[dv][mt][nt] = MFMA16(af[pa][mt], bf, acc[dv][mt][nt]);
              }
          }
        }
    }
    __syncthreads();
    if (i + 1 < r0 + 8) {
      int r = i + 3;
      stage_row(xs + ((r + 10) % 5) * SLOT_US, PSTR_32, xn, 32, r,
                (r >= 0 && r < 128), tid, 640);
      stage_row(ys, YPSTR, yn, 64, i + 1, true, tid, 640);
    }
  }

  float* Pn = P + (size_t)n * 800 * 64;
  int a = du + 2;
  #pragma unroll
  for (int dv = 0; dv < 5; ++dv)
    #pragma unroll
    for (int mt = 0; mt < 2; ++mt)
      #pragma unroll
      for (int nt = 0; nt < 2; ++nt)
        #pragma unroll
        for (int r = 0; r < 4; ++r) {
          int co = mh * 32 + mt * 16 + q * 4 + r;
          int ci = nt * 16 + lm;
          atomicAdd(&Pn[(ci * 25 + a * 5 + dv) * 64 + co], acc[dv][mt][nt][r]);
        }
}

// -------------------- Q[n,k1,k2] = R[n,c1,c2,b-a+4,f-e+4] (+ a on diag) ----
__global__ void k_buildQ(const float* __restrict__ R, float* __restrict__ Q,
                         const float* __restrict__ alpha, const float* __restrict__ reg) {
  int bid = blockIdx.x;
  int n = bid / 800, k1 = bid % 800;
  int c1 = k1 / 25, r1 = k1 % 25, a = r1 / 5, e = r1 % 5;
  float av = alpha_scale(alpha, reg, n);
  const float* Rn = R + ((size_t)n*32 + c1) * 32 * 81;
  float* Qrow = Q + ((size_t)n*800 + k1) * 800;
  for (int k2 = threadIdx.x; k2 < 800; k2 += 256) {
    int c2 = k2 / 25, r2 = k2 % 25, b = r2 / 5, f = r2 % 5;
    float v = Rn[c2*81 + (b - a + 4)*9 + (f - e + 4)];
    if (k2 == k1) v += av;
    Qrow[k2] = v;
  }
}

// -------------------- Cholesky: diag factor + explicit inverse --------------
__global__ __launch_bounds__(256) void k_chol_diag(float* __restrict__ Q,
                                                   float* __restrict__ Linv, int t) {
  int n = blockIdx.x;
  int tid = threadIdx.x;
  __shared__ float A[80*81];
  __shared__ float B[80*81];
  float* Qn = Q + (size_t)n * 640000;
  int base = t * 80;
  for (int idx = tid; idx < 6400; idx += 256) {
    int r = idx / 80, c = idx % 80;
    A[r*81 + c] = Qn[(base + r)*800 + base + c];
  }
  __syncthreads();
  for (int j = 0; j < 80; ++j) {
    if (tid == 0) A[j*81 + j] = sqrtf(A[j*81 + j]);
    __syncthreads();
    float dinv = 1.0f / A[j*81 + j];
    for (int i = j + 1 + tid; i < 80; i += 256) A[i*81 + j] *= dinv;
    __syncthreads();
    int m = 79 - j;
    for (int idx = tid; idx < m*m; idx += 256) {
      int i = j + 1 + idx / m, k = j + 1 + idx % m;
      if (k <= i) A[i*81 + k] -= A[i*81 + j] * A[k*81 + j];
    }
    __syncthreads();
  }
  if (tid < 80) {
    int j = tid;
    B[j*81 + j] = 1.0f / A[j*81 + j];
    for (int i = j + 1; i < 80; ++i) {
      float s = 0.0f;
      for (int k = j; k < i; ++k) s += A[i*81 + k] * B[k*81 + j];
      B[i*81 + j] = -s / A[i*81 + i];
    }
  }
  __syncthreads();
  float* Ln = Linv + ((size_t)n*10 + t) * 6400;
  for (int idx = tid; idx < 6400; idx += 256) {
    int r = idx / 80, c = idx % 80;
    Ln[idx] = (r >= c) ? B[r*81 + c] : 0.0f;
  }
}

// panel: W = A_panel * Linv^T  (overwrites panel with L)
__global__ __launch_bounds__(256) void k_chol_panel(float* __restrict__ Q,
                                                    const float* __restrict__ Linv,
                                                    int t, int nt) {
  int n = blockIdx.x / nt, it = blockIdx.x % nt;
  int R0 = 80*(t+1) + 80*it, C0 = 80*t;
  __shared__ float As[80*82];
  __shared__ float Bs[80*82];
  float* Qn = Q + (size_t)n * 640000;
  const float* Ln = Linv + ((size_t)n*10 + t) * 6400;
  int tid = threadIdx.x;
  for (int idx = tid; idx < 6400; idx += 256) {
    int r = idx / 80, c = idx % 80;
    As[r*82 + c] = Qn[(R0 + r)*800 + C0 + c];
    Bs[r*82 + c] = Ln[idx];
  }
  __syncthreads();
  int tc = tid & 15, tr = tid >> 4;
  float acc[5][5];
  #pragma unroll
  for (int a = 0; a < 5; ++a)
    #pragma unroll
    for (int b = 0; b < 5; ++b) acc[a][b] = 0.0f;
  for (int k = 0; k < 80; ++k) {
    float av[5], bv[5];
    #pragma unroll
    for (int d = 0; d < 5; ++d) { av[d] = As[(5*tr + d)*82 + k]; bv[d] = Bs[(5*tc + d)*82 + k]; }
    #pragma unroll
    for (int a = 0; a < 5; ++a)
      #pragma unroll
      for (int b = 0; b < 5; ++b) acc[a][b] += av[a] * bv[b];
  }
  #pragma unroll
  for (int a = 0; a < 5; ++a)
    #pragma unroll
    for (int b = 0; b < 5; ++b)
      Qn[(R0 + 5*tr + a)*800 + C0 + 5*tc + b] = acc[a][b];
}

// trailing: A_IJ -= W_I * W_J^T (lower tiles only)
__global__ __launch_bounds__(256) void k_chol_trail(float* __restrict__ Q, int t, int nt) {
  int ntile = nt * (nt + 1) / 2;
  int n = blockIdx.x / ntile;
  int rr = blockIdx.x % ntile;
  int i = 0;
  while (rr >= i + 1) { rr -= (i + 1); ++i; }
  int j = rr;
  int R0 = 80*(t+1+i), C0 = 80*(t+1+j), K0 = 80*t;
  __shared__ float Ws[80*82];
  __shared__ float Vs[80*82];
  float* Qn = Q + (size_t)n * 640000;
  int tid = threadIdx.x;
  for (int idx = tid; idx < 6400; idx += 256) {
    int r = idx / 80, c = idx % 80;
    Ws[r*82 + c] = Qn[(R0 + r)*800 + K0 + c];
    Vs[r*82 + c] = Qn[(C0 + r)*800 + K0 + c];
  }
  __syncthreads();
  int tc = tid & 15, tr = tid >> 4;
  float acc[5][5];
  #pragma unroll
  for (int a = 0; a < 5; ++a)
    #pragma unroll
    for (int b = 0; b < 5; ++b) acc[a][b] = 0.0f;
  for (int k = 0; k < 80; ++k) {
    float av[5], bv[5];
    #pragma unroll
    for (int d = 0; d < 5; ++d) { av[d] = Ws[(5*tr + d)*82 + k]; bv[d] = Vs[(5*tc + d)*82 + k]; }
    #pragma unroll
    for (int a = 0; a < 5; ++a)
      #pragma unroll
      for (int b = 0; b < 5; ++b) acc[a][b] += av[a] * bv[b];
  }
  #pragma unroll
  for (int a = 0; a < 5; ++a)
    #pragma unroll
    for (int b = 0; b < 5; ++b)
      Qn[(R0 + 5*tr + a)*800 + C0 + 5*tc + b] -= acc[a][b];
}

// -------------------- blocked triangular solves + output transpose ---------
__global__ __launch_bounds__(256) void k_solve(const float* __restrict__ Q,
                                               const float* __restrict__ Linv,
                                               const float* __restrict__ P,
                                               float* __restrict__ out) {
  int n = blockIdx.x >> 3;
  int g = blockIdx.x & 7;
  int tid = threadIdx.x;
  __shared__ float z[800*8];
  __shared__ float Lt[80*82];
  const float* Qn = Q + (size_t)n * 640000;

  for (int idx = tid; idx < 6400; idx += 256) {
    int k = idx >> 3, c = idx & 7;
    z[idx] = P[(n*800 + k)*64 + g*8 + c];
  }
  __syncthreads();

  for (int t = 0; t < 10; ++t) {
    for (int s = 0; s < t; ++s) {
      for (int idx = tid; idx < 6400; idx += 256)
        Lt[(idx/80)*82 + (idx%80)] = Qn[(80*t + idx/80)*800 + 80*s + idx%80];
      __syncthreads();
      for (int e = 0; e < 3; ++e) {
        int idx = tid + 256*e;
        if (idx < 640) {
          int c = idx & 7, r = idx >> 3;
          float acc = 0.0f;
          #pragma unroll 4
          for (int k = 0; k < 80; ++k) acc += Lt[r*82 + k] * z[(80*s + k)*8 + c];
          z[(80*t + r)*8 + c] -= acc;
        }
      }
      __syncthreads();
    }
    {
      const float* Ln = Linv + ((size_t)n*10 + t) * 6400;
      for (int idx = tid; idx < 6400; idx += 256)
        Lt[(idx/80)*82 + (idx%80)] = Ln[idx];
      __syncthreads();
      float tv[3];
      for (int e = 0; e < 3; ++e) {
        int idx = tid + 256*e;
        if (idx < 640) {
          int c = idx & 7, r = idx >> 3;
          float acc = 0.0f;
          #pragma unroll 4
          for (int k = 0; k < 80; ++k) acc += Lt[r*82 + k] * z[(80*t + k)*8 + c];
          tv[e] = acc;
        }
      }
      __syncthreads();
      for (int e = 0; e < 3; ++e) {
        int idx = tid + 256*e;
        if (idx < 640) { int c = idx & 7, r = idx >> 3; z[(80*t + r)*8 + c] = tv[e]; }
      }
      __syncthreads();
    }
  }

  for (int t = 9; t >= 0; --t) {
    for (int s = t + 1; s < 10; ++s) {
      for (int idx = tid; idx < 6400; idx += 256)
        Lt[(idx/80)*82 + (idx%80)] = Qn[(80*s + idx/80)*800 + 80*t + idx%80];
      __syncthreads();
      for (int e = 0; e < 3; ++e) {
        int idx = tid + 256*e;
        if (idx < 640) {
          int c = idx & 7, r = idx >> 3;
          float acc = 0.0f;
          #pragma unroll 4
          for (int k = 0; k < 80; ++k) acc += Lt[k*82 + r] * z[(80*s + k)*8 + c];
          z[(80*t + r)*8 + c] -= acc;
        }
      }
      __syncthreads();
    }
    {
      const float* Ln = Linv + ((size_t)n*10 + t) * 6400;
      for (int idx = tid; idx < 6400; idx += 256)
        Lt[(idx/80)*82 + (idx%80)] = Ln[idx];
      __syncthreads();
      float tv[3];
      for (int e = 0; e < 3; ++e) {
        int idx = tid + 256*e;
        if (idx < 640) {
          int c = idx & 7, r = idx >> 3;
          float acc = 0.0f;
          #pragma unroll 4
          for (int k = 0; k < 80; ++k) acc += Lt[k*82 + r] * z[(80*t + k)*8 + c];
          tv[e] = acc;
        }
      }
      __syncthreads();
      for (int e = 0; e < 3; ++e) {
        int idx = tid + 256*e;
        if (idx < 640) { int c = idx & 7, r = idx >> 3; z[(80*t + r)*8 + c] = tv[e]; }
      }
      __syncthreads();
    }
  }

  for (int idx = tid; idx < 6400; idx += 256) {
    int c = idx / 800, k = idx % 800;
    out[(size_t)(n*64 + g*8 + c)*800 + k] = z[k*8 + c];
  }
}

extern "C" void kernel_launch(void* const* d_in, const int* in_sizes, int n_in,
                              void* d_out, int out_size, void* d_ws, size_t ws_size,
                              hipStream_t stream) {
  const float* x     = (const float*)d_in[0];
  const float* d     = (const float*)d_in[1];
  const float* y     = (const float*)d_in[2];
  const float* alpha = (const float*)d_in[3];
  const float* reg   = (const float*)d_in[4];
  float* out = (float*)d_out;
  float* ws  = (float*)d_ws;

  float* R  = ws;
  float* Q  = ws + R_SZ;
  float* P  = ws + R_SZ + Q_SZ;
  float* Li = ws + R_SZ + Q_SZ + P_SZ;

  k_init<<<(R_SZ + P_SZ) / 256, 256, 0, stream>>>(R, P, d, alpha, reg);
  k_corrR_mfma<<<256, 576, 0, stream>>>(x, R);
  k_buildQ<<<16*800, 256, 0, stream>>>(R, Q, alpha, reg);
  k_corrP_mfma<<<256, 640, 0, stream>>>(x, y, P);

  for (int t = 0; t < 10; ++t) {
    k_chol_diag<<<16, 256, 0, stream>>>(Q, Li, t);
    int nt = 9 - t;
    if (nt > 0) {
      k_chol_panel<<<16*nt, 256, 0, stream>>>(Q, Li, t, nt);
      k_chol_trail<<<16*nt*(nt+1)/2, 256, 0, stream>>>(Q, t, nt);
    }
  }

  k_solve<<<128, 256, 0, stream>>>(Q, Li, P, out);
}